// Round 1
// baseline (293.365 us; speedup 1.0000x reference)
//
#include <hip/hip_runtime.h>
#include <hip/hip_bf16.h>
#include <math.h>

#define N_NODES 50000
#define N_EDGES 800000
#define IN_DIM  128
#define MEM_DIM 32
#define OUT_DIM 64
#define NB_SCAN ((N_NODES + 255) / 256)   // 196
#define SCALE   0.17677669529663687f      // 1/sqrt(32)

typedef __attribute__((ext_vector_type(8))) short bf16x8;
typedef __attribute__((ext_vector_type(4))) float f32x4;

__device__ __forceinline__ short f2bf(float f) {
    union { float f; unsigned u; } v; v.f = f;
    unsigned r = v.u + 0x7FFF + ((v.u >> 16) & 1);   // round-to-nearest-even
    return (short)(r >> 16);
}
__device__ __forceinline__ float lo16(unsigned u) { return __uint_as_float(u << 16); }
__device__ __forceinline__ float hi16(unsigned u) { return __uint_as_float(u & 0xffff0000u); }

// ---------------------------------------------------------------------------
// prep_k: transposed bf16 weight bank wtb[m][col][k] (B-frag = one dwordx4).
// m: 0=Wq*S, 1=Wk, 2=Wv, 3=Wskip, 4=WqE*S (We_k folded into Wq). Also zeroes
// the 8-replica histogram.
// ---------------------------------------------------------------------------
__global__ __launch_bounds__(256) void prep_k(
    const float* __restrict__ Wq, const float* __restrict__ Wk,
    const float* __restrict__ Wv, const float* __restrict__ Wskip,
    const float* __restrict__ We_k, unsigned short* __restrict__ wtb,
    int* __restrict__ cntr)
{
    const int i = blockIdx.x * 256 + threadIdx.x;   // 1600*256 = 409600
    if (i < 8 * N_NODES) cntr[i] = 0;
    if (i >= 51200) return;                         // 5*64*160
    const int m = i / 10240, rem = i % 10240, c = rem / 160, k = rem % 160;
    float v;
    if (m == 4) {
        const int h = c >> 5, kk = c & 31;
        v = 0.f;
        #pragma unroll
        for (int j = 0; j < 32; ++j)
            v += Wq[k * 64 + h * 32 + j] * We_k[kk * 64 + h * 32 + j];
        v *= SCALE;
    } else {
        const float* W = (m == 0) ? Wq : (m == 1) ? Wk : (m == 2) ? Wv : Wskip;
        v = W[k * 64 + c];
        if (m == 0) v *= SCALE;
    }
    wtb[(size_t)(m * 64 + c) * 160 + k] = (unsigned short)f2bf(v);
}

// ---------------------------------------------------------------------------
// node_gemm (+fused hist): blocks [0,3125) do the node GEMM
// [N,160]@[160, 5x64] -> qq (q|qek interleaved bf16), zkv (k|v interleaved
// bf16), out (skip, f32). Blocks [3125, 5625) do the 8-replica dst histogram
// (independent work, overlaps with the MFMA-bound GEMM).
// ---------------------------------------------------------------------------
__global__ __launch_bounds__(320) void node_gemm(
    const float* __restrict__ x, const float* __restrict__ mem,
    const unsigned short* __restrict__ wtb, const int* __restrict__ dst,
    unsigned short* __restrict__ qq, unsigned short* __restrict__ zkv,
    float* __restrict__ out, int* __restrict__ cntr)
{
    const int tid = threadIdx.x;
    if (blockIdx.x >= 3125) {
        const int e = (blockIdx.x - 3125) * 320 + tid;   // 2500*320 == E
        atomicAdd(&cntr[((e >> 8) & 7) * N_NODES + dst[e]], 1);
        return;
    }
    const int w    = tid >> 6;                  // 0..4
    const int lane = tid & 63;
    const int l15  = lane & 15;
    const int quad = lane >> 4;
    const int nb   = blockIdx.x * 16;

    const unsigned short* WmT = wtb + (size_t)w * 64 * 160;

    f32x4 acc[4];
    #pragma unroll
    for (int g = 0; g < 4; ++g) acc[g] = (f32x4)0.0f;

    const int node = nb + l15;
    #pragma unroll
    for (int kb = 0; kb < 5; ++kb) {
        const float* zsrc = (kb < 4)
            ? (x   + (size_t)node * IN_DIM  + kb * 32 + quad * 8)
            : (mem + (size_t)node * MEM_DIM + quad * 8);
        bf16x8 afrag;
        #pragma unroll
        for (int j = 0; j < 8; ++j) afrag[j] = f2bf(zsrc[j]);

        const int k0 = kb * 32 + quad * 8;
        #pragma unroll
        for (int g = 0; g < 4; ++g) {
            const bf16x8 bfrag = *(const bf16x8*)(WmT + (size_t)(16 * g + l15) * 160 + k0);
            acc[g] = __builtin_amdgcn_mfma_f32_16x16x32_bf16(afrag, bfrag, acc[g], 0, 0, 0);
        }
    }
    #pragma unroll
    for (int g = 0; g < 4; ++g) {
        #pragma unroll
        for (int r = 0; r < 4; ++r) {
            const int nrow = nb + quad * 4 + r;
            const int col  = 16 * g + l15;
            if (w == 3)
                out[(size_t)nrow * OUT_DIM + col] = acc[g][r];
            else if (w == 0)
                qq[(size_t)nrow * 128 + 2 * col] = (unsigned short)f2bf(acc[g][r]);
            else if (w == 4)
                qq[(size_t)nrow * 128 + 2 * col + 1] = (unsigned short)f2bf(acc[g][r]);
            else   // w==1 -> k (lo slot), w==2 -> v (hi slot)
                zkv[(size_t)nrow * 128 + 2 * col + (w == 2)] =
                    (unsigned short)f2bf(acc[g][r]);
        }
    }
}

// ---------------------------------------------------------------------------
// scan1: reduce 8 replica counts -> in-place exclusive replica offsets + deg;
// block-exclusive-scan of totals. scan2: scan the 196 block sums.
// ---------------------------------------------------------------------------
__global__ __launch_bounds__(256) void scan1_k(int* __restrict__ cntr,
                                               int* __restrict__ base,
                                               int* __restrict__ bsum,
                                               int* __restrict__ deg)
{
    __shared__ int sh[256];
    const int i = blockIdx.x * 256 + threadIdx.x;
    int tot = 0;
    if (i < N_NODES) {
        int off = 0;
        #pragma unroll
        for (int r = 0; r < 8; ++r) {
            const int c = cntr[r * N_NODES + i];
            cntr[r * N_NODES + i] = off;
            off += c;
        }
        tot = off;
        deg[i] = tot;
    }
    sh[threadIdx.x] = tot;
    __syncthreads();
    int val = tot;
    for (int off = 1; off < 256; off <<= 1) {
        const int y = (threadIdx.x >= off) ? sh[threadIdx.x - off] : 0;
        __syncthreads();
        val += y; sh[threadIdx.x] = val;
        __syncthreads();
    }
    if (i < N_NODES) base[i] = val - tot;
    if (threadIdx.x == 255) bsum[blockIdx.x] = val;
}

__global__ __launch_bounds__(256) void scan2_k(int* __restrict__ bsum)
{
    __shared__ int sh[256];
    const int i = threadIdx.x;
    const int v = (i < NB_SCAN) ? bsum[i] : 0;
    sh[i] = v;
    __syncthreads();
    int val = v;
    for (int off = 1; off < 256; off <<= 1) {
        const int y = (i >= off) ? sh[i - off] : 0;
        __syncthreads();
        val += y; sh[i] = val;
        __syncthreads();
    }
    if (i < NB_SCAN) bsum[i] = val - v;
}

// ---------------------------------------------------------------------------
// scatter_k: pure 8B scatter of (src, t) into dst-sorted order. Position
// comes from the scanned offsets; the within-(node,replica) rank is obtained
// by atomically bumping the post-scan cntr offsets (absorbs the old rank[]
// round-trip). No table gathers here anymore — scoring moved to agg_k.
// ---------------------------------------------------------------------------
__global__ __launch_bounds__(256) void scatter_k(
    const int* __restrict__ srcA, const int* __restrict__ dstA,
    const float* __restrict__ tA,
    const int* __restrict__ base, const int* __restrict__ bsum,
    int* __restrict__ cntr, float2* __restrict__ edata2)
{
    const int e = blockIdx.x * 256 + threadIdx.x;   // 3125*256 == E
    const int d = dstA[e];
    const int pos = base[d] + bsum[d >> 8]
                  + atomicAdd(&cntr[((e >> 8) & 7) * N_NODES + d], 1);
    float2 rc;
    rc.x = __int_as_float(srcA[e]);
    rc.y = tA[e];
    edata2[pos] = rc;
}

// ---------------------------------------------------------------------------
// agg_k: one WAVE per node; scoring FUSED here (dst-side q/qek loaded once
// per node instead of once per edge — 16x redundancy removed). Chunks of 16
// sorted (src,t) records -> wave-private LDS. Per record: ONE 4B/lane gather
// of the interleaved k|v pair, te = cos(t*w+b) (shared between score and pte
// accumulation), p = half-wave shfl_xor reduce of q*k + qek*te, pe = exp(p).
// kv gather software-pipelined one record ahead. Epilogue fuses We_v.
// ---------------------------------------------------------------------------
__global__ __launch_bounds__(256) void agg_k(
    const float2* __restrict__ edata2, const int* __restrict__ base,
    const int* __restrict__ bsum, const int* __restrict__ degA,
    const float* __restrict__ w_time, const float* __restrict__ b_time,
    const unsigned short* __restrict__ qq,
    const unsigned short* __restrict__ zkv,
    const float* __restrict__ We_v, float* __restrict__ out)
{
    __shared__ float recs[4][64];               // 1 KB; wave-private strips
    const int tid  = threadIdx.x;
    const int w    = tid >> 6;
    const int lane = tid & 63;
    const int n    = blockIdx.x * 4 + w;

    const int b0  = base[n] + bsum[n >> 8];
    const int deg = degA[n];
    float* rec = &recs[w][0];

    const float wtA = w_time[lane & 31];
    const float btA = b_time[lane & 31];

    // dst-side: q and qek for this node, once (lane = head*32 + dim)
    const unsigned qv = *(const unsigned*)(qq + (size_t)n * 128 + 2 * lane);
    const float q_l   = lo16(qv);
    const float qek_l = hi16(qv);

    float av = 0.f, pte = 0.f, lp = 0.f;

    // prefetch chunk 0
    float2 rc;
    if (lane < 16 && deg > 0)
        rc = edata2[min(b0 + lane, N_EDGES - 1)];

    for (int ch = 0; ch < deg; ch += 16) {
        if (lane < 16) *(float2*)(rec + lane * 2) = rc;
        // prefetch next chunk while processing this one
        const int nch = ch + 16;
        if (lane < 16 && nch < deg)
            rc = edata2[min(b0 + nch + lane, N_EDGES - 1)];

        const int cc = min(16, deg - ch);

        // 1-deep pipeline on the kv gather
        float2 r = *(const float2*)rec;
        unsigned kv = *(const unsigned*)(zkv +
                        (size_t)__float_as_int(r.x) * 128 + 2 * lane);
        for (int j = 0; j < cc; ++j) {
            float2 rn = r; unsigned kvn = kv;
            if (j + 1 < cc) {
                rn  = *(const float2*)(rec + 2 * (j + 1));
                kvn = *(const unsigned*)(zkv +
                        (size_t)__float_as_int(rn.x) * 128 + 2 * lane);
            }
            const float te = __cosf(r.y * wtA + btA);
            float pr = q_l * lo16(kv) + qek_l * te;   // scale pre-folded
            pr += __shfl_xor(pr, 1);
            pr += __shfl_xor(pr, 2);
            pr += __shfl_xor(pr, 4);
            pr += __shfl_xor(pr, 8);
            pr += __shfl_xor(pr, 16);                 // per-head sum (32-lane half)
            const float pe = __expf(pr);
            av  += pe * hi16(kv);
            pte += pe * te;
            lp  += pe;
            r = rn; kv = kvn;
        }
    }

    // ---- fused We_v epilogue ----
    rec[lane] = pte;                            // rec[h*32+dim] layout
    float wev[32];
    #pragma unroll
    for (int k = 0; k < 32; ++k) wev[k] = We_v[k * 64 + lane];

    const float inv = (lp > 0.f) ? 1.f / lp : 0.f;
    const float* pl = rec + (lane >> 5) * 32;
    float dot = 0.f;
    #pragma unroll
    for (int k = 0; k < 32; ++k) dot += pl[k] * wev[k];

    out[(size_t)n * OUT_DIM + lane] += (av + dot) * inv;   // skip already there
}

extern "C" void kernel_launch(void* const* d_in, const int* in_sizes, int n_in,
                              void* d_out, int out_size, void* d_ws, size_t ws_size,
                              hipStream_t stream) {
    (void)in_sizes; (void)n_in; (void)out_size; (void)ws_size;
    const int*   src    = (const int*)d_in[0];
    const int*   dst    = (const int*)d_in[1];
    const float* t      = (const float*)d_in[2];
    const float* x      = (const float*)d_in[3];
    const float* mem    = (const float*)d_in[4];
    const float* w_time = (const float*)d_in[5];
    const float* b_time = (const float*)d_in[6];
    const float* Wq     = (const float*)d_in[7];
    const float* Wk     = (const float*)d_in[8];
    const float* Wv     = (const float*)d_in[9];
    const float* We_k   = (const float*)d_in[10];
    const float* We_v   = (const float*)d_in[11];
    const float* Wskip  = (const float*)d_in[12];

    // workspace layout (16B-aligned chunks)
    char* p = (char*)d_ws;
    unsigned short* zkv = (unsigned short*)p; p += (size_t)N_NODES * 128 * 2; // 12.8 MB (k|v interleaved)
    unsigned short* qq  = (unsigned short*)p; p += (size_t)N_NODES * 128 * 2; // 12.8 MB (q|qek interleaved)
    unsigned short* wtb = (unsigned short*)p; p += (size_t)5 * 64 * 160 * 2;  // 100 KB
    float2* edata2 = (float2*)p; p += (size_t)N_EDGES * 8;                    // 6.4 MB
    int*  cntr  = (int*)p;   p += (size_t)8 * N_NODES * 4;   // zeroed in prep_k
    int*  base  = (int*)p;   p += (size_t)N_NODES * 4;
    int*  deg   = (int*)p;   p += (size_t)N_NODES * 4;
    int*  bsum  = (int*)p;   p += 256 * 4;
    float* out  = (float*)d_out;

    prep_k   <<<1600, 256, 0, stream>>>(Wq, Wk, Wv, Wskip, We_k, wtb, cntr);
    node_gemm<<<5625, 320, 0, stream>>>(x, mem, wtb, dst, qq, zkv, out, cntr);
    scan1_k  <<<NB_SCAN, 256, 0, stream>>>(cntr, base, bsum, deg);
    scan2_k  <<<1, 256, 0, stream>>>(bsum);
    scatter_k<<<N_EDGES / 256, 256, 0, stream>>>(src, dst, t, base, bsum, cntr, edata2);
    agg_k    <<<N_NODES / 4, 256, 0, stream>>>(edata2, base, bsum, deg,
                                               w_time, b_time, qq, zkv, We_v, out);
}

// Round 2
// 265.541 us; speedup vs baseline: 1.1048x; 1.1048x over previous
//
#include <hip/hip_runtime.h>
#include <hip/hip_bf16.h>
#include <math.h>

#define N_NODES 50000
#define N_EDGES 800000
#define IN_DIM  128
#define MEM_DIM 32
#define OUT_DIM 64
#define NB_SCAN ((N_NODES + 255) / 256)   // 196
#define SCALE   0.17677669529663687f      // 1/sqrt(32)

typedef __attribute__((ext_vector_type(8))) short bf16x8;
typedef __attribute__((ext_vector_type(4))) float f32x4;

__device__ __forceinline__ short f2bf(float f) {
    union { float f; unsigned u; } v; v.f = f;
    unsigned r = v.u + 0x7FFF + ((v.u >> 16) & 1);   // round-to-nearest-even
    return (short)(r >> 16);
}
__device__ __forceinline__ float lo16(unsigned u) { return __uint_as_float(u << 16); }
__device__ __forceinline__ float hi16(unsigned u) { return __uint_as_float(u & 0xffff0000u); }

// Cross-lane add via DPP (VALU pipe, not LDS). CTRL: 0xB1=quad_perm xor1,
// 0x4E=quad_perm xor2, 0x124=row_ror:4, 0x128=row_ror:8.
template <int CTRL>
__device__ __forceinline__ float dpp_mov(float x) {
    return __int_as_float(__builtin_amdgcn_update_dpp(
        0, __float_as_int(x), CTRL, 0xF, 0xF, true));
}
// xor16 within each 32-lane half (BitMode: xor=16, and=0x1F)
__device__ __forceinline__ float swz16(float x) {
    return __int_as_float(__builtin_amdgcn_ds_swizzle(__float_as_int(x), 0x401F));
}
// sum over the lane's 32-lane half: 4 DPP adds + 1 swizzle
__device__ __forceinline__ float half_reduce(float pr) {
    pr += dpp_mov<0xB1>(pr);
    pr += dpp_mov<0x4E>(pr);
    pr += dpp_mov<0x124>(pr);
    pr += dpp_mov<0x128>(pr);
    pr += swz16(pr);
    return pr;
}

// ---------------------------------------------------------------------------
// prep_k: transposed bf16 weight bank wtb[m][col][k] (B-frag = one dwordx4).
// m: 0=Wq*S, 1=Wk, 2=Wv, 3=Wskip, 4=WqE*S (We_k folded into Wq). Also zeroes
// the 8-replica histogram.
// ---------------------------------------------------------------------------
__global__ __launch_bounds__(256) void prep_k(
    const float* __restrict__ Wq, const float* __restrict__ Wk,
    const float* __restrict__ Wv, const float* __restrict__ Wskip,
    const float* __restrict__ We_k, unsigned short* __restrict__ wtb,
    int* __restrict__ cntr)
{
    const int i = blockIdx.x * 256 + threadIdx.x;   // 1600*256 = 409600
    if (i < 8 * N_NODES) cntr[i] = 0;
    if (i >= 51200) return;                         // 5*64*160
    const int m = i / 10240, rem = i % 10240, c = rem / 160, k = rem % 160;
    float v;
    if (m == 4) {
        const int h = c >> 5, kk = c & 31;
        v = 0.f;
        #pragma unroll
        for (int j = 0; j < 32; ++j)
            v += Wq[k * 64 + h * 32 + j] * We_k[kk * 64 + h * 32 + j];
        v *= SCALE;
    } else {
        const float* W = (m == 0) ? Wq : (m == 1) ? Wk : (m == 2) ? Wv : Wskip;
        v = W[k * 64 + c];
        if (m == 0) v *= SCALE;
    }
    wtb[(size_t)(m * 64 + c) * 160 + k] = (unsigned short)f2bf(v);
}

// ---------------------------------------------------------------------------
// node_gemm (+fused hist): blocks [0,3125) do the node GEMM
// [N,160]@[160, 5x64] -> qq (q|qek interleaved bf16), zkv (k|v interleaved
// bf16), out (skip, f32). Blocks [3125, 5625) do the 8-replica dst histogram.
// ---------------------------------------------------------------------------
__global__ __launch_bounds__(320) void node_gemm(
    const float* __restrict__ x, const float* __restrict__ mem,
    const unsigned short* __restrict__ wtb, const int* __restrict__ dst,
    unsigned short* __restrict__ qq, unsigned short* __restrict__ zkv,
    float* __restrict__ out, int* __restrict__ cntr)
{
    const int tid = threadIdx.x;
    if (blockIdx.x >= 3125) {
        const int e = (blockIdx.x - 3125) * 320 + tid;   // 2500*320 == E
        atomicAdd(&cntr[((e >> 8) & 7) * N_NODES + dst[e]], 1);
        return;
    }
    const int w    = tid >> 6;                  // 0..4
    const int lane = tid & 63;
    const int l15  = lane & 15;
    const int quad = lane >> 4;
    const int nb   = blockIdx.x * 16;

    const unsigned short* WmT = wtb + (size_t)w * 64 * 160;

    f32x4 acc[4];
    #pragma unroll
    for (int g = 0; g < 4; ++g) acc[g] = (f32x4)0.0f;

    const int node = nb + l15;
    #pragma unroll
    for (int kb = 0; kb < 5; ++kb) {
        const float* zsrc = (kb < 4)
            ? (x   + (size_t)node * IN_DIM  + kb * 32 + quad * 8)
            : (mem + (size_t)node * MEM_DIM + quad * 8);
        bf16x8 afrag;
        #pragma unroll
        for (int j = 0; j < 8; ++j) afrag[j] = f2bf(zsrc[j]);

        const int k0 = kb * 32 + quad * 8;
        #pragma unroll
        for (int g = 0; g < 4; ++g) {
            const bf16x8 bfrag = *(const bf16x8*)(WmT + (size_t)(16 * g + l15) * 160 + k0);
            acc[g] = __builtin_amdgcn_mfma_f32_16x16x32_bf16(afrag, bfrag, acc[g], 0, 0, 0);
        }
    }
    #pragma unroll
    for (int g = 0; g < 4; ++g) {
        #pragma unroll
        for (int r = 0; r < 4; ++r) {
            const int nrow = nb + quad * 4 + r;
            const int col  = 16 * g + l15;
            if (w == 3)
                out[(size_t)nrow * OUT_DIM + col] = acc[g][r];
            else if (w == 0)
                qq[(size_t)nrow * 128 + 2 * col] = (unsigned short)f2bf(acc[g][r]);
            else if (w == 4)
                qq[(size_t)nrow * 128 + 2 * col + 1] = (unsigned short)f2bf(acc[g][r]);
            else   // w==1 -> k (lo slot), w==2 -> v (hi slot)
                zkv[(size_t)nrow * 128 + 2 * col + (w == 2)] =
                    (unsigned short)f2bf(acc[g][r]);
        }
    }
}

// ---------------------------------------------------------------------------
// scan1 / scan2: exclusive scans of the 8-replica histogram.
// ---------------------------------------------------------------------------
__global__ __launch_bounds__(256) void scan1_k(int* __restrict__ cntr,
                                               int* __restrict__ base,
                                               int* __restrict__ bsum,
                                               int* __restrict__ deg)
{
    __shared__ int sh[256];
    const int i = blockIdx.x * 256 + threadIdx.x;
    int tot = 0;
    if (i < N_NODES) {
        int off = 0;
        #pragma unroll
        for (int r = 0; r < 8; ++r) {
            const int c = cntr[r * N_NODES + i];
            cntr[r * N_NODES + i] = off;
            off += c;
        }
        tot = off;
        deg[i] = tot;
    }
    sh[threadIdx.x] = tot;
    __syncthreads();
    int val = tot;
    for (int off = 1; off < 256; off <<= 1) {
        const int y = (threadIdx.x >= off) ? sh[threadIdx.x - off] : 0;
        __syncthreads();
        val += y; sh[threadIdx.x] = val;
        __syncthreads();
    }
    if (i < N_NODES) base[i] = val - tot;
    if (threadIdx.x == 255) bsum[blockIdx.x] = val;
}

__global__ __launch_bounds__(256) void scan2_k(int* __restrict__ bsum)
{
    __shared__ int sh[256];
    const int i = threadIdx.x;
    const int v = (i < NB_SCAN) ? bsum[i] : 0;
    sh[i] = v;
    __syncthreads();
    int val = v;
    for (int off = 1; off < 256; off <<= 1) {
        const int y = (i >= off) ? sh[i - off] : 0;
        __syncthreads();
        val += y; sh[i] = val;
        __syncthreads();
    }
    if (i < NB_SCAN) bsum[i] = val - v;
}

// ---------------------------------------------------------------------------
// scatter_k: pure 8B scatter of (src, t) into dst-sorted order; rank via
// atomic bump of the post-scan replica offsets.
// ---------------------------------------------------------------------------
__global__ __launch_bounds__(256) void scatter_k(
    const int* __restrict__ srcA, const int* __restrict__ dstA,
    const float* __restrict__ tA,
    const int* __restrict__ base, const int* __restrict__ bsum,
    int* __restrict__ cntr, float2* __restrict__ edata2)
{
    const int e = blockIdx.x * 256 + threadIdx.x;   // 3125*256 == E
    const int d = dstA[e];
    const int pos = base[d] + bsum[d >> 8]
                  + atomicAdd(&cntr[((e >> 8) & 7) * N_NODES + d], 1);
    float2 rc;
    rc.x = __int_as_float(srcA[e]);
    rc.y = tA[e];
    edata2[pos] = rc;
}

// ---------------------------------------------------------------------------
// agg_k: one WAVE per node, scoring fused. v2: the per-record 32-lane score
// reduce is 4 DPP adds (VALU pipe) + ONE ds_swizzle (was 5 shfl = 5 LDS ops).
// Records are read as uniform broadcast global loads (L1-resident line; no
// LDS staging). kv gathers issued 8-deep per group so L2 latency is hidden.
// Epilogue pte@We_v uses ds_read_b128.
// ---------------------------------------------------------------------------
__global__ __launch_bounds__(256) void agg_k(
    const float2* __restrict__ edata2, const int* __restrict__ base,
    const int* __restrict__ bsum, const int* __restrict__ degA,
    const float* __restrict__ w_time, const float* __restrict__ b_time,
    const unsigned short* __restrict__ qq,
    const unsigned short* __restrict__ zkv,
    const float* __restrict__ We_v, float* __restrict__ out)
{
    __shared__ float recs[4][64];               // epilogue strips only
    const int tid  = threadIdx.x;
    const int w    = tid >> 6;
    const int lane = tid & 63;
    const int n    = blockIdx.x * 4 + w;

    const int b0  = base[n] + bsum[n >> 8];
    const int deg = degA[n];

    const float wtA = w_time[lane & 31];
    const float btA = b_time[lane & 31];

    // dst-side: q and qek for this node, once (lane = head*32 + dim)
    const unsigned qv = *(const unsigned*)(qq + (size_t)n * 128 + 2 * lane);
    const float q_l   = lo16(qv);
    const float qek_l = hi16(qv);

    float av = 0.f, pte = 0.f, lp = 0.f;

    int g0 = 0;
    // full groups of 8: batch-issue record loads, then kv gathers, then
    // compute (unrolled; independent score chains overlap)
    for (; g0 + 8 <= deg; g0 += 8) {
        float2 r[8];
        #pragma unroll
        for (int j = 0; j < 8; ++j) r[j] = edata2[b0 + g0 + j];
        unsigned kv[8];
        #pragma unroll
        for (int j = 0; j < 8; ++j)
            kv[j] = *(const unsigned*)(zkv +
                      (size_t)__float_as_int(r[j].x) * 128 + 2 * lane);
        #pragma unroll
        for (int j = 0; j < 8; ++j) {
            const float te = __cosf(r[j].y * wtA + btA);
            float pr = q_l * lo16(kv[j]) + qek_l * te;  // scale pre-folded
            pr = half_reduce(pr);
            const float pe = __expf(pr);
            av  += pe * hi16(kv[j]);
            pte += pe * te;
            lp  += pe;
        }
    }
    // tail (< 8 records)
    for (; g0 < deg; ++g0) {
        const float2 rj = edata2[b0 + g0];
        const unsigned kvj = *(const unsigned*)(zkv +
                      (size_t)__float_as_int(rj.x) * 128 + 2 * lane);
        const float te = __cosf(rj.y * wtA + btA);
        float pr = q_l * lo16(kvj) + qek_l * te;
        pr = half_reduce(pr);
        const float pe = __expf(pr);
        av  += pe * hi16(kvj);
        pte += pe * te;
        lp  += pe;
    }

    // ---- fused We_v epilogue (vectorized LDS reads) ----
    float* rec = &recs[w][0];
    rec[lane] = pte;                            // rec[h*32+dim] layout
    float wev[32];
    #pragma unroll
    for (int k = 0; k < 32; ++k) wev[k] = We_v[k * 64 + lane];

    const float inv = (lp > 0.f) ? 1.f / lp : 0.f;
    const float4* pv = (const float4*)(rec + (lane >> 5) * 32);
    float dot = 0.f;
    #pragma unroll
    for (int k = 0; k < 8; ++k) {
        const float4 c = pv[k];
        dot += c.x * wev[4 * k]     + c.y * wev[4 * k + 1]
             + c.z * wev[4 * k + 2] + c.w * wev[4 * k + 3];
    }

    out[(size_t)n * OUT_DIM + lane] += (av + dot) * inv;   // skip already there
}

extern "C" void kernel_launch(void* const* d_in, const int* in_sizes, int n_in,
                              void* d_out, int out_size, void* d_ws, size_t ws_size,
                              hipStream_t stream) {
    (void)in_sizes; (void)n_in; (void)out_size; (void)ws_size;
    const int*   src    = (const int*)d_in[0];
    const int*   dst    = (const int*)d_in[1];
    const float* t      = (const float*)d_in[2];
    const float* x      = (const float*)d_in[3];
    const float* mem    = (const float*)d_in[4];
    const float* w_time = (const float*)d_in[5];
    const float* b_time = (const float*)d_in[6];
    const float* Wq     = (const float*)d_in[7];
    const float* Wk     = (const float*)d_in[8];
    const float* Wv     = (const float*)d_in[9];
    const float* We_k   = (const float*)d_in[10];
    const float* We_v   = (const float*)d_in[11];
    const float* Wskip  = (const float*)d_in[12];

    // workspace layout (16B-aligned chunks)
    char* p = (char*)d_ws;
    unsigned short* zkv = (unsigned short*)p; p += (size_t)N_NODES * 128 * 2; // 12.8 MB (k|v interleaved)
    unsigned short* qq  = (unsigned short*)p; p += (size_t)N_NODES * 128 * 2; // 12.8 MB (q|qek interleaved)
    unsigned short* wtb = (unsigned short*)p; p += (size_t)5 * 64 * 160 * 2;  // 100 KB
    float2* edata2 = (float2*)p; p += (size_t)N_EDGES * 8;                    // 6.4 MB
    int*  cntr  = (int*)p;   p += (size_t)8 * N_NODES * 4;   // zeroed in prep_k
    int*  base  = (int*)p;   p += (size_t)N_NODES * 4;
    int*  deg   = (int*)p;   p += (size_t)N_NODES * 4;
    int*  bsum  = (int*)p;   p += 256 * 4;
    float* out  = (float*)d_out;

    prep_k   <<<1600, 256, 0, stream>>>(Wq, Wk, Wv, Wskip, We_k, wtb, cntr);
    node_gemm<<<5625, 320, 0, stream>>>(x, mem, wtb, dst, qq, zkv, out, cntr);
    scan1_k  <<<NB_SCAN, 256, 0, stream>>>(cntr, base, bsum, deg);
    scan2_k  <<<1, 256, 0, stream>>>(bsum);
    scatter_k<<<N_EDGES / 256, 256, 0, stream>>>(src, dst, t, base, bsum, cntr, edata2);
    agg_k    <<<N_NODES / 4, 256, 0, stream>>>(edata2, base, bsum, deg,
                                               w_time, b_time, qq, zkv, We_v, out);
}

// Round 3
// 252.635 us; speedup vs baseline: 1.1612x; 1.0511x over previous
//
#include <hip/hip_runtime.h>
#include <hip/hip_bf16.h>
#include <math.h>

#define N_NODES 50000
#define N_EDGES 800000
#define IN_DIM  128
#define MEM_DIM 32
#define OUT_DIM 64
#define NB_SCAN ((N_NODES + 255) / 256)   // 196
#define SCALE   0.17677669529663687f      // 1/sqrt(32)
#define LDS_AROW 168                      // padded A-tile row stride (elems); 84 dwords -> conflict-free

typedef __attribute__((ext_vector_type(8))) short bf16x8;
typedef __attribute__((ext_vector_type(4))) float f32x4;

__device__ __forceinline__ short f2bf(float f) {
    union { float f; unsigned u; } v; v.f = f;
    unsigned r = v.u + 0x7FFF + ((v.u >> 16) & 1);   // round-to-nearest-even
    return (short)(r >> 16);
}
__device__ __forceinline__ float lo16(unsigned u) { return __uint_as_float(u << 16); }
__device__ __forceinline__ float hi16(unsigned u) { return __uint_as_float(u & 0xffff0000u); }

// Cross-lane add via DPP (VALU pipe, not LDS). CTRL: 0xB1=quad_perm xor1,
// 0x4E=quad_perm xor2, 0x124=row_ror:4, 0x128=row_ror:8.
template <int CTRL>
__device__ __forceinline__ float dpp_mov(float x) {
    return __int_as_float(__builtin_amdgcn_update_dpp(
        0, __float_as_int(x), CTRL, 0xF, 0xF, true));
}
// xor16 within each 32-lane half (BitMode: xor=16, and=0x1F)
__device__ __forceinline__ float swz16(float x) {
    return __int_as_float(__builtin_amdgcn_ds_swizzle(__float_as_int(x), 0x401F));
}
// sum over the lane's 32-lane half: 4 DPP adds + 1 swizzle
__device__ __forceinline__ float half_reduce(float pr) {
    pr += dpp_mov<0xB1>(pr);
    pr += dpp_mov<0x4E>(pr);
    pr += dpp_mov<0x124>(pr);
    pr += dpp_mov<0x128>(pr);
    pr += swz16(pr);
    return pr;
}

// ---------------------------------------------------------------------------
// prep_k: transposed bf16 weight bank wtb[m][col][k] (B-frag = one dwordx4).
// m: 0=Wq*S, 1=Wk, 2=Wv, 3=Wskip, 4=WqE*S (We_k folded into Wq). Also zeroes
// the 8-replica histogram.
// ---------------------------------------------------------------------------
__global__ __launch_bounds__(256) void prep_k(
    const float* __restrict__ Wq, const float* __restrict__ Wk,
    const float* __restrict__ Wv, const float* __restrict__ Wskip,
    const float* __restrict__ We_k, unsigned short* __restrict__ wtb,
    int* __restrict__ cntr)
{
    const int i = blockIdx.x * 256 + threadIdx.x;   // 1600*256 = 409600
    if (i < 8 * N_NODES) cntr[i] = 0;
    if (i >= 51200) return;                         // 5*64*160
    const int m = i / 10240, rem = i % 10240, c = rem / 160, k = rem % 160;
    float v;
    if (m == 4) {
        const int h = c >> 5, kk = c & 31;
        v = 0.f;
        #pragma unroll
        for (int j = 0; j < 32; ++j)
            v += Wq[k * 64 + h * 32 + j] * We_k[kk * 64 + h * 32 + j];
        v *= SCALE;
    } else {
        const float* W = (m == 0) ? Wq : (m == 1) ? Wk : (m == 2) ? Wv : Wskip;
        v = W[k * 64 + c];
        if (m == 0) v *= SCALE;
    }
    wtb[(size_t)(m * 64 + c) * 160 + k] = (unsigned short)f2bf(v);
}

// ---------------------------------------------------------------------------
// node_gemm v3 (+fused hist): blocks [0,3125) do the node GEMM.
// Per block (16 nodes): coalesced float4 staging of x|mem -> bf16 LDS A-tile
// (converted ONCE, shared by all 5 waves; padded stride kills bank conflicts
// and the old 16-txn/instr uncoalesced A-loads). Waves MFMA from LDS, stage
// results into LDS out-tiles, then three contiguous 4KB dwordx4 block copies
// (full cache lines -> kills the 2-byte scattered-store RMW inflation).
// Blocks [3125, 5625) do the 8-replica dst histogram.
// ---------------------------------------------------------------------------
__global__ __launch_bounds__(320) void node_gemm(
    const float* __restrict__ x, const float* __restrict__ mem,
    const unsigned short* __restrict__ wtb, const int* __restrict__ dst,
    unsigned short* __restrict__ qq, unsigned short* __restrict__ zkv,
    float* __restrict__ out, int* __restrict__ cntr)
{
    const int tid = threadIdx.x;
    if (blockIdx.x >= 3125) {
        const int e = (blockIdx.x - 3125) * 320 + tid;   // 2500*320 == E
        atomicAdd(&cntr[((e >> 8) & 7) * N_NODES + dst[e]], 1);
        return;
    }
    __shared__ unsigned short sA[16 * LDS_AROW];    // 5.25 KB bf16 in-tile
    __shared__ unsigned short sQQ[16 * 128];        // 4 KB
    __shared__ unsigned short sKV[16 * 128];        // 4 KB
    __shared__ float          sOUT[16 * 64];        // 4 KB

    const int nb = blockIdx.x * 16;

    // ---- cooperative coalesced stage: x (16x128) + mem (16x32) -> sA ----
    // 640 float4 total over 320 threads (2 each).
    for (int i = tid; i < 640; i += 320) {
        float4 f;
        int row, dim;
        if (i < 512) {                       // x part: 16 rows x 32 float4
            row = i >> 5; dim = (i & 31) * 4;
            f = *(const float4*)(x + (size_t)(nb + row) * IN_DIM + dim);
        } else {                             // mem part: 16 rows x 8 float4
            const int j = i - 512;
            row = j >> 3; dim = 128 + (j & 7) * 4;
            f = *(const float4*)(mem + (size_t)(nb + row) * MEM_DIM + (dim - 128));
        }
        unsigned short* d = sA + row * LDS_AROW + dim;
        d[0] = (unsigned short)f2bf(f.x); d[1] = (unsigned short)f2bf(f.y);
        d[2] = (unsigned short)f2bf(f.z); d[3] = (unsigned short)f2bf(f.w);
    }
    __syncthreads();

    const int w    = tid >> 6;                  // 0..4 (matrix id)
    const int lane = tid & 63;
    const int l15  = lane & 15;
    const int quad = lane >> 4;

    const unsigned short* WmT = wtb + (size_t)w * 64 * 160;

    f32x4 acc[4];
    #pragma unroll
    for (int g = 0; g < 4; ++g) acc[g] = (f32x4)0.0f;

    #pragma unroll
    for (int kb = 0; kb < 5; ++kb) {
        const int k0 = kb * 32 + quad * 8;
        const bf16x8 afrag = *(const bf16x8*)(sA + l15 * LDS_AROW + k0);
        #pragma unroll
        for (int g = 0; g < 4; ++g) {
            const bf16x8 bfrag = *(const bf16x8*)(WmT + (size_t)(16 * g + l15) * 160 + k0);
            acc[g] = __builtin_amdgcn_mfma_f32_16x16x32_bf16(afrag, bfrag, acc[g], 0, 0, 0);
        }
    }

    // ---- stage results into LDS out-tiles ----
    #pragma unroll
    for (int g = 0; g < 4; ++g) {
        #pragma unroll
        for (int r = 0; r < 4; ++r) {
            const int row = quad * 4 + r;
            const int col = 16 * g + l15;
            if (w == 3)
                sOUT[row * 64 + col] = acc[g][r];
            else if (w == 0)
                sQQ[row * 128 + 2 * col] = (unsigned short)f2bf(acc[g][r]);
            else if (w == 4)
                sQQ[row * 128 + 2 * col + 1] = (unsigned short)f2bf(acc[g][r]);
            else   // w==1 -> k (lo slot), w==2 -> v (hi slot)
                sKV[row * 128 + 2 * col + (w == 2)] = (unsigned short)f2bf(acc[g][r]);
        }
    }
    __syncthreads();

    // ---- contiguous full-line epilogue: 3 x 4KB block copies ----
    for (int i = tid; i < 256; i += 320) {
        ((uint4*)(qq + (size_t)nb * 128))[i]      = ((const uint4*)sQQ)[i];
        ((uint4*)(zkv + (size_t)nb * 128))[i]     = ((const uint4*)sKV)[i];
        ((float4*)(out + (size_t)nb * OUT_DIM))[i] = ((const float4*)sOUT)[i];
    }
}

// ---------------------------------------------------------------------------
// scan1 / scan2: exclusive scans of the 8-replica histogram.
// ---------------------------------------------------------------------------
__global__ __launch_bounds__(256) void scan1_k(int* __restrict__ cntr,
                                               int* __restrict__ base,
                                               int* __restrict__ bsum,
                                               int* __restrict__ deg)
{
    __shared__ int sh[256];
    const int i = blockIdx.x * 256 + threadIdx.x;
    int tot = 0;
    if (i < N_NODES) {
        int off = 0;
        #pragma unroll
        for (int r = 0; r < 8; ++r) {
            const int c = cntr[r * N_NODES + i];
            cntr[r * N_NODES + i] = off;
            off += c;
        }
        tot = off;
        deg[i] = tot;
    }
    sh[threadIdx.x] = tot;
    __syncthreads();
    int val = tot;
    for (int off = 1; off < 256; off <<= 1) {
        const int y = (threadIdx.x >= off) ? sh[threadIdx.x - off] : 0;
        __syncthreads();
        val += y; sh[threadIdx.x] = val;
        __syncthreads();
    }
    if (i < N_NODES) base[i] = val - tot;
    if (threadIdx.x == 255) bsum[blockIdx.x] = val;
}

__global__ __launch_bounds__(256) void scan2_k(int* __restrict__ bsum)
{
    __shared__ int sh[256];
    const int i = threadIdx.x;
    const int v = (i < NB_SCAN) ? bsum[i] : 0;
    sh[i] = v;
    __syncthreads();
    int val = v;
    for (int off = 1; off < 256; off <<= 1) {
        const int y = (i >= off) ? sh[i - off] : 0;
        __syncthreads();
        val += y; sh[i] = val;
        __syncthreads();
    }
    if (i < NB_SCAN) bsum[i] = val - v;
}

// ---------------------------------------------------------------------------
// scatter_k: pure 8B scatter of (src, t) into dst-sorted order; rank via
// atomic bump of the post-scan replica offsets.
// ---------------------------------------------------------------------------
__global__ __launch_bounds__(256) void scatter_k(
    const int* __restrict__ srcA, const int* __restrict__ dstA,
    const float* __restrict__ tA,
    const int* __restrict__ base, const int* __restrict__ bsum,
    int* __restrict__ cntr, float2* __restrict__ edata2)
{
    const int e = blockIdx.x * 256 + threadIdx.x;   // 3125*256 == E
    const int d = dstA[e];
    const int pos = base[d] + bsum[d >> 8]
                  + atomicAdd(&cntr[((e >> 8) & 7) * N_NODES + d], 1);
    float2 rc;
    rc.x = __int_as_float(srcA[e]);
    rc.y = tA[e];
    edata2[pos] = rc;
}

// ---------------------------------------------------------------------------
// agg_k: one WAVE per node, scoring fused. Per-record 32-lane score reduce is
// 4 DPP adds (VALU pipe) + ONE ds_swizzle. Records read as uniform broadcast
// global loads; kv gathers issued 8-deep so L2 latency is hidden.
// ---------------------------------------------------------------------------
__global__ __launch_bounds__(256) void agg_k(
    const float2* __restrict__ edata2, const int* __restrict__ base,
    const int* __restrict__ bsum, const int* __restrict__ degA,
    const float* __restrict__ w_time, const float* __restrict__ b_time,
    const unsigned short* __restrict__ qq,
    const unsigned short* __restrict__ zkv,
    const float* __restrict__ We_v, float* __restrict__ out)
{
    __shared__ float recs[4][64];               // epilogue strips only
    const int tid  = threadIdx.x;
    const int w    = tid >> 6;
    const int lane = tid & 63;
    const int n    = blockIdx.x * 4 + w;

    const int b0  = base[n] + bsum[n >> 8];
    const int deg = degA[n];

    const float wtA = w_time[lane & 31];
    const float btA = b_time[lane & 31];

    // dst-side: q and qek for this node, once (lane = head*32 + dim)
    const unsigned qv = *(const unsigned*)(qq + (size_t)n * 128 + 2 * lane);
    const float q_l   = lo16(qv);
    const float qek_l = hi16(qv);

    float av = 0.f, pte = 0.f, lp = 0.f;

    int g0 = 0;
    for (; g0 + 8 <= deg; g0 += 8) {
        float2 r[8];
        #pragma unroll
        for (int j = 0; j < 8; ++j) r[j] = edata2[b0 + g0 + j];
        unsigned kv[8];
        #pragma unroll
        for (int j = 0; j < 8; ++j)
            kv[j] = *(const unsigned*)(zkv +
                      (size_t)__float_as_int(r[j].x) * 128 + 2 * lane);
        #pragma unroll
        for (int j = 0; j < 8; ++j) {
            const float te = __cosf(r[j].y * wtA + btA);
            float pr = q_l * lo16(kv[j]) + qek_l * te;  // scale pre-folded
            pr = half_reduce(pr);
            const float pe = __expf(pr);
            av  += pe * hi16(kv[j]);
            pte += pe * te;
            lp  += pe;
        }
    }
    for (; g0 < deg; ++g0) {
        const float2 rj = edata2[b0 + g0];
        const unsigned kvj = *(const unsigned*)(zkv +
                      (size_t)__float_as_int(rj.x) * 128 + 2 * lane);
        const float te = __cosf(rj.y * wtA + btA);
        float pr = q_l * lo16(kvj) + qek_l * te;
        pr = half_reduce(pr);
        const float pe = __expf(pr);
        av  += pe * hi16(kvj);
        pte += pe * te;
        lp  += pe;
    }

    // ---- fused We_v epilogue (vectorized LDS reads) ----
    float* rec = &recs[w][0];
    rec[lane] = pte;                            // rec[h*32+dim] layout
    float wev[32];
    #pragma unroll
    for (int k = 0; k < 32; ++k) wev[k] = We_v[k * 64 + lane];

    const float inv = (lp > 0.f) ? 1.f / lp : 0.f;
    const float4* pv = (const float4*)(rec + (lane >> 5) * 32);
    float dot = 0.f;
    #pragma unroll
    for (int k = 0; k < 8; ++k) {
        const float4 c = pv[k];
        dot += c.x * wev[4 * k]     + c.y * wev[4 * k + 1]
             + c.z * wev[4 * k + 2] + c.w * wev[4 * k + 3];
    }

    out[(size_t)n * OUT_DIM + lane] += (av + dot) * inv;   // skip already there
}

extern "C" void kernel_launch(void* const* d_in, const int* in_sizes, int n_in,
                              void* d_out, int out_size, void* d_ws, size_t ws_size,
                              hipStream_t stream) {
    (void)in_sizes; (void)n_in; (void)out_size; (void)ws_size;
    const int*   src    = (const int*)d_in[0];
    const int*   dst    = (const int*)d_in[1];
    const float* t      = (const float*)d_in[2];
    const float* x      = (const float*)d_in[3];
    const float* mem    = (const float*)d_in[4];
    const float* w_time = (const float*)d_in[5];
    const float* b_time = (const float*)d_in[6];
    const float* Wq     = (const float*)d_in[7];
    const float* Wk     = (const float*)d_in[8];
    const float* Wv     = (const float*)d_in[9];
    const float* We_k   = (const float*)d_in[10];
    const float* We_v   = (const float*)d_in[11];
    const float* Wskip  = (const float*)d_in[12];

    // workspace layout (16B-aligned chunks)
    char* p = (char*)d_ws;
    unsigned short* zkv = (unsigned short*)p; p += (size_t)N_NODES * 128 * 2; // 12.8 MB (k|v interleaved)
    unsigned short* qq  = (unsigned short*)p; p += (size_t)N_NODES * 128 * 2; // 12.8 MB (q|qek interleaved)
    unsigned short* wtb = (unsigned short*)p; p += (size_t)5 * 64 * 160 * 2;  // 100 KB
    float2* edata2 = (float2*)p; p += (size_t)N_EDGES * 8;                    // 6.4 MB
    int*  cntr  = (int*)p;   p += (size_t)8 * N_NODES * 4;   // zeroed in prep_k
    int*  base  = (int*)p;   p += (size_t)N_NODES * 4;
    int*  deg   = (int*)p;   p += (size_t)N_NODES * 4;
    int*  bsum  = (int*)p;   p += 256 * 4;
    float* out  = (float*)d_out;

    prep_k   <<<1600, 256, 0, stream>>>(Wq, Wk, Wv, Wskip, We_k, wtb, cntr);
    node_gemm<<<5625, 320, 0, stream>>>(x, mem, wtb, dst, qq, zkv, out, cntr);
    scan1_k  <<<NB_SCAN, 256, 0, stream>>>(cntr, base, bsum, deg);
    scan2_k  <<<1, 256, 0, stream>>>(bsum);
    scatter_k<<<N_EDGES / 256, 256, 0, stream>>>(src, dst, t, base, bsum, cntr, edata2);
    agg_k    <<<N_NODES / 4, 256, 0, stream>>>(edata2, base, bsum, deg,
                                               w_time, b_time, qq, zkv, We_v, out);
}